// Round 3
// baseline (113.637 us; speedup 1.0000x reference)
//
#include <hip/hip_runtime.h>

// FullAttention N=2, L=S=2048, H=8, D=64, fp32 in/out.
// v12: single fused kernel; convert_kernel and the workspace are GONE.
//  v10/v11 post-mortem: both staging-traffic theories null -> fattn is
//  latency-bound, and the measured window is dominated by fixed costs:
//  harness re-poison of the 256MiB workspace (fillBufferAligned, 268MB,
//  ~44us, top-5 every round) + two launches + inter-kernel gap + convert.
//  v12 removes every piece we control: one launch, no d_ws use, no
//  bf16-tile round-trip. Each sh-stream's 4 waves reg-stage the next tile's
//  fp32 K/V (16 floats/thread), convert in-register, ds_write into the SAME
//  validated swizzled layouts (K octet^phi(row); V d-pair rows). T14 split:
//  global loads issued before compute(t), cvt+ds_write after -> latency
//  hidden. Same 16-iter single-barrier double-buffer, same MFMA fragment
//  math, same no-max softmax, same 3-round merge as v11.
//  Structure: 1024 thr = 16 waves = 4 qgrp (128 q) x 4 sh (512 keys each).
//  Grid (16,16) = 256 WGs = 1 WG/CU. LDS 64KB. XCD remap kept (2 nh/XCD ->
//  2MB fp32 working set, L2-resident).

#define L_Q 2048
#define S_K 2048

typedef __attribute__((ext_vector_type(8)))  short short8;
typedef __attribute__((ext_vector_type(4)))  float floatx4;
typedef __attribute__((ext_vector_type(16))) float floatx16;

__device__ __forceinline__ short bf16_of(float f) {
  return __builtin_bit_cast(short, (__bf16)f);
}

__device__ __forceinline__ short8 cvt8(floatx4 a, floatx4 b) {
  short8 r;
  r[0] = bf16_of(a[0]); r[1] = bf16_of(a[1]); r[2] = bf16_of(a[2]); r[3] = bf16_of(a[3]);
  r[4] = bf16_of(b[0]); r[5] = bf16_of(b[1]); r[6] = bf16_of(b[2]); r[7] = bf16_of(b[3]);
  return r;
}

__device__ __forceinline__ unsigned pack2(float lo, float hi) {
  return (unsigned)(unsigned short)bf16_of(lo) |
         ((unsigned)(unsigned short)bf16_of(hi) << 16);
}

__device__ __forceinline__ int phi(int r) {          // octet XOR swizzle
  return ((r >> 3) & 3) ^ ((r & 3) << 1);
}

__device__ __forceinline__ int swap23(int m) {       // swap bits 2 and 3
  return (m & 19) | ((m & 4) << 1) | ((m & 8) >> 1);
}

__global__ __launch_bounds__(1024, 4)
void fattn12_kernel(const float* __restrict__ qg, const float* __restrict__ kg,
                    const float* __restrict__ vg, float* __restrict__ og)
{
  // [sh 0..3][buf 0..1][8 KB] = 64 KB; reused for the final in-WG merge
  __shared__ __align__(16) char smem[65536];

  const int tid  = threadIdx.x;        // 0..1023
  const int wv   = tid >> 6;           // 0..15
  const int lane = tid & 63;
  const int m32  = lane & 31;
  const int hi   = lane >> 5;
  const int qgrp = wv & 3;             // 32-query tile within the 128-q block
  const int sh   = wv >> 2;            // S-stream 0..3: keys [sh*512, +512)

  // XCD-aware remap: 256 WGs; xcd = flat&7 consumes nh in {2*xcd, 2*xcd+1}.
  const int flat = blockIdx.x + 16 * blockIdx.y;   // 0..255
  const int xcd  = flat & 7;
  const int i    = flat >> 3;                      // 0..31
  const int nh   = (xcd << 1) | (i >> 4);          // 0..15
  const int qblk = i & 15;                         // 0..15
  const int n  = nh >> 3, h = nh & 7;
  const int q0w = qblk * 128 + qgrp * 32;

  const float SCALE = 0.18033688011112042f;   // (1/sqrt(64)) * log2(e)

  // Q B-frags (32x32x16): lane holds Q[q = m32][d = c*16 + hi*8 + j]
  short8 qf[4];
  {
    const float* qp = qg + (((size_t)n * L_Q + q0w + m32) * 8 + h) * 64 + hi * 8;
#pragma unroll
    for (int c = 0; c < 4; ++c) {
      floatx4 f0 = *(const floatx4*)(qp + c * 16);
      floatx4 f1 = *(const floatx4*)(qp + c * 16 + 4);
      f0 *= SCALE; f1 *= SCALE;
      qf[c] = cvt8(f0, f1);
    }
  }

  // ---- staging roles: u = 0..255 within this sh-stream's 4 waves.
  // u<128: K thread (row r, d-chunk c4), exactly convert_kernel's K mapping.
  // u>=128: V thread (key pair kp, d-oct dq), exactly its V mapping.
  // Branch is wave-uniform (qgrp uniform per wave).
  const int u   = qgrp * 64 + lane;
  const bool isK = (u < 128);
  const int r   = u >> 2, c4 = u & 3;              // K role
  const int t2  = u - 128, kp = t2 & 15, dq = t2 >> 4;  // V role

  const float* gsrc;
  int offA;                         // float offset of the second load pair
  int ldsK1 = 0, ldsK2 = 0;         // byte offsets within the 8KB tile
  int ldsV[8];
  const size_t key0 = (size_t)sh * 512;            // stream's first key
  if (isK) {
    gsrc = kg + (((size_t)n * S_K + key0 + r) * 8 + h) * 64 + c4 * 16;
    offA = 8;
    ldsK1 = (r * 8 + ((2 * c4)     ^ phi(r))) * 16;
    ldsK2 = (r * 8 + ((2 * c4 + 1) ^ phi(r))) * 16;
#pragma unroll
    for (int j = 0; j < 8; ++j) ldsV[j] = 0;       // keep regs defined
  } else {
    gsrc = vg + (((size_t)n * S_K + key0 + 2 * kp) * 8 + h) * 64 + dq * 8;
    offA = 512;                                    // key+1 is 8*64 floats on
#pragma unroll
    for (int j = 0; j < 8; ++j) {
      const int d = dq * 8 + j, P = d >> 1;
      const int po = (((d & 1) * 4) + (kp >> 2)) ^ phi(P);
      ldsV[j] = 4096 + ((P * 8 + po) * 8 + (kp & 3) * 2) * 2;
    }
  }
  const size_t TSTEP = 32 * 8 * 64;                // floats per 32-key tile

  floatx4 s0, s1, s2, s3;                          // staged fp32 regs
#define LOADT(t_) {                                                            \
    const float* p_ = gsrc + (size_t)(t_) * TSTEP;                             \
    s0 = *(const floatx4*)(p_);        s1 = *(const floatx4*)(p_ + 4);         \
    s2 = *(const floatx4*)(p_ + offA); s3 = *(const floatx4*)(p_ + offA + 4); }

#define CVTWRITE(buf_) {                                                       \
    char* b_ = smem + (sh * 2 + (buf_)) * 8192;                                \
    if (isK) {                                                                 \
      *(short8*)(b_ + ldsK1) = cvt8(s0, s1);                                   \
      *(short8*)(b_ + ldsK2) = cvt8(s2, s3);                                   \
    } else {                                                                   \
      _Pragma("unroll")                                                        \
      for (int j_ = 0; j_ < 8; ++j_) {                                         \
        const float lo_ = (j_ < 4) ? s0[j_] : s1[j_ - 4];                      \
        const float hi_ = (j_ < 4) ? s2[j_] : s3[j_ - 4];                      \
        *(unsigned*)(b_ + ldsV[j_]) = pack2(lo_, hi_);                         \
      }                                                                        \
    } }

  floatx16 o_acc[2];
  o_acc[0] = (floatx16)(0.f); o_acc[1] = (floatx16)(0.f);
  float psum = 0.f;

  // K A-operand: row m holds phys key swap23(m) so C regs feed the PV B
  const int krow = swap23(m32);
  const int kphi = phi(krow);

  LOADT(0);
  CVTWRITE(0);                       // buf0; no reader before first barrier

#pragma unroll 1
  for (int t = 0; t < 16; ++t) {
    __syncthreads();                 // buf[t&1] complete; prev reads done
    if (t + 1 < 16) LOADT(t + 1);    // async: consumed after compute

    const short* kt = (const short*)(smem + (sh * 2 + (t & 1)) * 8192);
    const short* vt = kt + 2048;

    // QK: C[m][q] = sum_d K[swap23(m)][d] * Qs[q][d], 4 c-steps of K=16
    floatx16 acc = (floatx16)(0.f);
#pragma unroll
    for (int c = 0; c < 4; ++c) {
      short8 kf = *(const short8*)(kt + (krow * 8 + ((2 * c + hi) ^ kphi)) * 8);
      acc = __builtin_amdgcn_mfma_f32_32x32x16_bf16(kf, qf[c], acc, 0, 0, 0);
    }
    // no-max softmax; C regs ks*8+j (lane half hi) = PV B element j, step ks
    short8 bfq[2];
    float ps0 = 0.f, ps1 = 0.f;
#pragma unroll
    for (int rr = 0; rr < 16; ++rr) {
      float p = __builtin_amdgcn_exp2f(acc[rr]);
      if (rr & 1) ps1 += p; else ps0 += p;
      bfq[rr >> 3][rr & 7] = bf16_of(p);
    }
    psum += ps0 + ps1;
    // PV: O[d'][q] += sum_key V^T[d'][key] * P[key][q]
#pragma unroll
    for (int dm = 0; dm < 2; ++dm) {
      const int d = dm * 32 + m32, P = d >> 1;
#pragma unroll
      for (int ks = 0; ks < 2; ++ks) {
        const int po = (((d & 1) * 4) + ks * 2 + hi) ^ phi(P);
        short8 vf = *(const short8*)(vt + (P * 8 + po) * 8);
        o_acc[dm] = __builtin_amdgcn_mfma_f32_32x32x16_bf16(vf, bfq[ks], o_acc[dm], 0, 0, 0);
      }
    }

    if (t + 1 < 16) CVTWRITE((t + 1) & 1);  // writes other buffer; barrier
  }                                         // at t+1 publishes it

  // psum: lane and lane^32 hold complementary key subsets of query m32
  psum += __shfl_xor(psum, 32);

  // ---- merge the 4 sh streams in LDS (plain sums, no-max softmax)
  // 3 rounds: sh==s2 writes its 4 qgrp partials, sh==0 accumulates.
  float* opart = (float*)smem;                 // [4 slots][32 q][68]
  float* lpart = (float*)(smem + 34816);       // [4 slots][32 q]
#pragma unroll 1
  for (int s2 = 1; s2 < 4; ++s2) {
    __syncthreads();                           // prev round / compute dead
    if (sh == s2) {
#pragma unroll
      for (int dm = 0; dm < 2; ++dm)
#pragma unroll
        for (int g = 0; g < 4; ++g) {
          floatx4 v4 = {o_acc[dm][4 * g], o_acc[dm][4 * g + 1],
                        o_acc[dm][4 * g + 2], o_acc[dm][4 * g + 3]};
          *(floatx4*)(opart + qgrp * 2176 + m32 * 68 + dm * 32 + 8 * g + 4 * hi) = v4;
        }
      if (hi == 0) lpart[qgrp * 32 + m32] = psum;
    }
    __syncthreads();
    if (sh == 0) {
      psum += lpart[qgrp * 32 + m32];
#pragma unroll
      for (int dm = 0; dm < 2; ++dm)
#pragma unroll
        for (int g = 0; g < 4; ++g) {
          floatx4 v4 = *(const floatx4*)(opart + qgrp * 2176 + m32 * 68 +
                                         dm * 32 + 8 * g + 4 * hi);
          o_acc[dm][4 * g]     += v4[0];
          o_acc[dm][4 * g + 1] += v4[1];
          o_acc[dm][4 * g + 2] += v4[2];
          o_acc[dm][4 * g + 3] += v4[3];
        }
    }
  }
  if (sh == 0) {
    const float inv = 1.0f / psum;
    float* op = og + (((size_t)n * L_Q + q0w + m32) * 8 + h) * 64;
#pragma unroll
    for (int dm = 0; dm < 2; ++dm)
#pragma unroll
      for (int g = 0; g < 4; ++g) {
        floatx4 v4 = {o_acc[dm][4 * g] * inv, o_acc[dm][4 * g + 1] * inv,
                      o_acc[dm][4 * g + 2] * inv, o_acc[dm][4 * g + 3] * inv};
        *(floatx4*)(op + dm * 32 + 8 * g + 4 * hi) = v4;
      }
  }
}

extern "C" void kernel_launch(void* const* d_in, const int* in_sizes, int n_in,
                              void* d_out, int out_size, void* d_ws, size_t ws_size,
                              hipStream_t stream) {
  const float* q = (const float*)d_in[0];
  const float* k = (const float*)d_in[1];
  const float* v = (const float*)d_in[2];
  float* out = (float*)d_out;
  (void)d_ws; (void)ws_size;

  fattn12_kernel<<<dim3(16, 16), dim3(1024), 0, stream>>>(q, k, v, out);
}